// Round 1
// baseline (1498.478 us; speedup 1.0000x reference)
//
#include <hip/hip_runtime.h>
#include <hip/hip_bf16.h>
#include <stdint.h>

#define HIDDEN  2048
#define INTER   8192
#define COMPACT 8192
#define NTOK    16384

typedef unsigned short ushort_t;
typedef float  f32x4  __attribute__((ext_vector_type(4)));
typedef __bf16 bf16x8 __attribute__((ext_vector_type(8)));

// ---------------------------------------------------------------------------
// Scratch lives in static device globals, NOT d_ws.
// Rationale: the prior failure (first check passed, post-timing diverged
// deterministically) matches a 192 MiB footprint exceeding ws_size, with the
// dn region's OOB writes clobbering an input buffer after the first call.
// Static .bss is owned by this module for the process lifetime; every region
// read here is fully rewritten on every call, so replay semantics are exact.
// ---------------------------------------------------------------------------
__device__ __align__(16) ushort_t g_xc[(size_t)COMPACT * HIDDEN]; // 32 MiB bf16
__device__ __align__(16) ushort_t g_wg[(size_t)INTER * HIDDEN];   // 32 MiB bf16
__device__ __align__(16) ushort_t g_wu[(size_t)INTER * HIDDEN];   // 32 MiB bf16
__device__ __align__(16) ushort_t g_wd[(size_t)HIDDEN * INTER];   // 32 MiB bf16
__device__ __align__(16) float    g_dn[(size_t)COMPACT * HIDDEN]; // 64 MiB fp32

// fp32 -> bf16 round-to-nearest-even (finite inputs)
__device__ __forceinline__ ushort_t f2bf(float f) {
    uint32_t u = __builtin_bit_cast(uint32_t, f);
    uint32_t lsb = (u >> 16) & 1u;
    u += 0x7fffu + lsb;
    return (ushort_t)(u >> 16);
}

// Async global->LDS, 16B per lane. HW semantics: wave-uniform base + lane*16,
// which matches lds ptr = base + tid*16 with contiguous (unpadded) layout.
__device__ __forceinline__ void async_cp16(const void* g, void* l) {
    __builtin_amdgcn_global_load_lds(
        (__attribute__((address_space(1))) void*)((void*)g),
        (__attribute__((address_space(3))) void*)l,
        16, 0, 0);
}

// ---------------------------------------------------------------------------
// Prepass 1: gather + fp32->bf16.  g_xc[c,:] = bf16(x[fg[c],:])
// One block per compact row; thread t converts 8 floats.
// ---------------------------------------------------------------------------
__global__ __launch_bounds__(256)
void k_gather_cast(const float* __restrict__ x, const int* __restrict__ fg)
{
    const int c = blockIdx.x;
    const int t = threadIdx.x;            // 256 threads * 8 floats = 2048
    const float4* src = (const float4*)(x + (size_t)fg[c] * HIDDEN) + (t << 1);
    float4 a = src[0], b = src[1];
    union { ushort_t u[8]; uint4 v; } p;
    p.u[0] = f2bf(a.x); p.u[1] = f2bf(a.y); p.u[2] = f2bf(a.z); p.u[3] = f2bf(a.w);
    p.u[4] = f2bf(b.x); p.u[5] = f2bf(b.y); p.u[6] = f2bf(b.z); p.u[7] = f2bf(b.w);
    *((uint4*)(g_xc + (size_t)c * HIDDEN) + t) = p.v;
}

// ---------------------------------------------------------------------------
// Prepass 2: plain fp32->bf16 cast, 8 elements/thread.  W selects the dest
// device-global (0=Wg, 1=Wu, 2=Wd) so no device-symbol address is needed host-side.
// ---------------------------------------------------------------------------
template<int W>
__global__ __launch_bounds__(256)
void k_cast(const float* __restrict__ src)
{
    ushort_t* __restrict__ dst = (W == 0) ? g_wg : (W == 1) ? g_wu : g_wd;
    const size_t g = (size_t)blockIdx.x * 256 + threadIdx.x;
    const float4* s = (const float4*)src + (g << 1);
    float4 a = s[0], b = s[1];
    union { ushort_t u[8]; uint4 v; } p;
    p.u[0] = f2bf(a.x); p.u[1] = f2bf(a.y); p.u[2] = f2bf(a.z); p.u[3] = f2bf(a.w);
    p.u[4] = f2bf(b.x); p.u[5] = f2bf(b.y); p.u[6] = f2bf(b.z); p.u[7] = f2bf(b.w);
    *((uint4*)dst + g) = p.v;
}

// ---------------------------------------------------------------------------
// Kernel 1: gate/up GEMM + silu-mul.  h[c,i] = silu(xc.Wg) * (xc.Wu)
// NT GEMM, M=COMPACT, N=INTER, K=HIDDEN. 128x128 tile, BK=32, 4 waves.
// h (bf16, 128 MiB) lives in d_out — dead until k_scatter overwrites it.
// ---------------------------------------------------------------------------
__global__ __launch_bounds__(256, 2)
void k_gateup(ushort_t* __restrict__ h)
{
    __shared__ __align__(16) ushort_t As[128 * 32];
    __shared__ __align__(16) ushort_t Bg[128 * 32];
    __shared__ __align__(16) ushort_t Bu[128 * 32];

    const int tid = threadIdx.x;
    const int bm0 = blockIdx.y << 7;
    const int bn0 = blockIdx.x << 7;

    const int sr = tid >> 2;
    const int sc = (tid & 3) << 3;

    const ushort_t* pa0 = g_xc + (size_t)(bm0 + sr) * HIDDEN + sc;
    const ushort_t* pa1 = pa0 + (size_t)64 * HIDDEN;
    const ushort_t* pg0 = g_wg + (size_t)(bn0 + sr) * HIDDEN + sc;
    const ushort_t* pg1 = pg0 + (size_t)64 * HIDDEN;
    const ushort_t* pu0 = g_wu + (size_t)(bn0 + sr) * HIDDEN + sc;
    const ushort_t* pu1 = pu0 + (size_t)64 * HIDDEN;

    ushort_t* lA0 = &As[tid << 3];
    ushort_t* lA1 = &As[(tid + 256) << 3];
    ushort_t* lG0 = &Bg[tid << 3];
    ushort_t* lG1 = &Bg[(tid + 256) << 3];
    ushort_t* lU0 = &Bu[tid << 3];
    ushort_t* lU1 = &Bu[(tid + 256) << 3];

    const int lane = tid & 63;
    const int wv = tid >> 6;
    const int wm = (wv & 1) << 6;
    const int wn = (wv >> 1) << 6;
    const int lr = lane & 15;
    const int kq = (lane >> 4) << 3;

    f32x4 accg[4][4], accu[4][4];
    #pragma unroll
    for (int i = 0; i < 4; ++i)
        #pragma unroll
        for (int j = 0; j < 4; ++j) {
            accg[i][j] = (f32x4){0.f, 0.f, 0.f, 0.f};
            accu[i][j] = (f32x4){0.f, 0.f, 0.f, 0.f};
        }

    for (int k0 = 0; k0 < HIDDEN; k0 += 32) {
        async_cp16(pa0, lA0); async_cp16(pa1, lA1);
        async_cp16(pg0, lG0); async_cp16(pg1, lG1);
        async_cp16(pu0, lU0); async_cp16(pu1, lU1);
        pa0 += 32; pa1 += 32; pg0 += 32; pg1 += 32; pu0 += 32; pu1 += 32;
        __syncthreads();

        bf16x8 af[4], gf[4], uf[4];
        #pragma unroll
        for (int i = 0; i < 4; ++i) {
            af[i] = *(const bf16x8*)&As[(wm + (i << 4) + lr) * 32 + kq];
            gf[i] = *(const bf16x8*)&Bg[(wn + (i << 4) + lr) * 32 + kq];
            uf[i] = *(const bf16x8*)&Bu[(wn + (i << 4) + lr) * 32 + kq];
        }
        #pragma unroll
        for (int i = 0; i < 4; ++i)
            #pragma unroll
            for (int j = 0; j < 4; ++j) {
                accg[i][j] = __builtin_amdgcn_mfma_f32_16x16x32_bf16(af[i], gf[j], accg[i][j], 0, 0, 0);
                accu[i][j] = __builtin_amdgcn_mfma_f32_16x16x32_bf16(af[i], uf[j], accu[i][j], 0, 0, 0);
            }
        __syncthreads();
    }

    // C/D layout (m89-verified): col = lane&15, row = (lane>>4)*4 + reg.
    const int orow0 = bm0 + wm + ((lane >> 4) << 2);
    const int ocol  = bn0 + wn + lr;
    #pragma unroll
    for (int i = 0; i < 4; ++i)
        #pragma unroll
        for (int j = 0; j < 4; ++j)
            #pragma unroll
            for (int r = 0; r < 4; ++r) {
                float g = accg[i][j][r];
                float u = accu[i][j][r];
                float s = g / (1.0f + __expf(-g));   // silu
                size_t off = (size_t)(orow0 + (i << 4) + r) * INTER + (size_t)(ocol + (j << 4));
                h[off] = f2bf(s * u);
            }
}

// ---------------------------------------------------------------------------
// Kernel 2: down GEMM.  g_dn[c,hc] = h[c,:] . Wd[hc,:]   (fp32 output)
// NT GEMM, M=COMPACT, N=HIDDEN, K=INTER.
// ---------------------------------------------------------------------------
__global__ __launch_bounds__(256, 2)
void k_down(const ushort_t* __restrict__ hbuf)
{
    __shared__ __align__(16) ushort_t As[128 * 32];
    __shared__ __align__(16) ushort_t Bs[128 * 32];

    const int tid = threadIdx.x;
    const int bm0 = blockIdx.y << 7;
    const int bn0 = blockIdx.x << 7;
    const int sr = tid >> 2;
    const int sc = (tid & 3) << 3;

    const ushort_t* pa0 = hbuf + (size_t)(bm0 + sr) * INTER + sc;
    const ushort_t* pa1 = pa0 + (size_t)64 * INTER;
    const ushort_t* pb0 = g_wd + (size_t)(bn0 + sr) * INTER + sc;
    const ushort_t* pb1 = pb0 + (size_t)64 * INTER;

    ushort_t* lA0 = &As[tid << 3];
    ushort_t* lA1 = &As[(tid + 256) << 3];
    ushort_t* lB0 = &Bs[tid << 3];
    ushort_t* lB1 = &Bs[(tid + 256) << 3];

    const int lane = tid & 63;
    const int wv = tid >> 6;
    const int wm = (wv & 1) << 6;
    const int wn = (wv >> 1) << 6;
    const int lr = lane & 15;
    const int kq = (lane >> 4) << 3;

    f32x4 acc[4][4];
    #pragma unroll
    for (int i = 0; i < 4; ++i)
        #pragma unroll
        for (int j = 0; j < 4; ++j)
            acc[i][j] = (f32x4){0.f, 0.f, 0.f, 0.f};

    for (int k0 = 0; k0 < INTER; k0 += 32) {
        async_cp16(pa0, lA0); async_cp16(pa1, lA1);
        async_cp16(pb0, lB0); async_cp16(pb1, lB1);
        pa0 += 32; pa1 += 32; pb0 += 32; pb1 += 32;
        __syncthreads();

        bf16x8 af[4], bfr[4];
        #pragma unroll
        for (int i = 0; i < 4; ++i) {
            af[i]  = *(const bf16x8*)&As[(wm + (i << 4) + lr) * 32 + kq];
            bfr[i] = *(const bf16x8*)&Bs[(wn + (i << 4) + lr) * 32 + kq];
        }
        #pragma unroll
        for (int i = 0; i < 4; ++i)
            #pragma unroll
            for (int j = 0; j < 4; ++j)
                acc[i][j] = __builtin_amdgcn_mfma_f32_16x16x32_bf16(af[i], bfr[j], acc[i][j], 0, 0, 0);
        __syncthreads();
    }

    const int orow0 = bm0 + wm + ((lane >> 4) << 2);
    const int ocol  = bn0 + wn + lr;
    #pragma unroll
    for (int i = 0; i < 4; ++i)
        #pragma unroll
        for (int j = 0; j < 4; ++j)
            #pragma unroll
            for (int r = 0; r < 4; ++r) {
                size_t off = (size_t)(orow0 + (i << 4) + r) * HIDDEN + (size_t)(ocol + (j << 4));
                g_dn[off] = acc[i][j][r];
            }
}

// ---------------------------------------------------------------------------
// Kernel 3: scatter fp32 rows. out[n,:] = g_dn[sc[n],:]
// One float4 per thread; 2048 cols = 512 float4 per row.
// ---------------------------------------------------------------------------
__global__ __launch_bounds__(256)
void k_scatter(const int* __restrict__ sc,
               float4* __restrict__ out)
{
    const int gid = blockIdx.x * 256 + threadIdx.x;
    const int row = gid >> 9;
    const int ch  = gid & 511;
    const int s = sc[row];
    out[((size_t)row << 9) + ch] = ((const float4*)g_dn)[((size_t)s << 9) + ch];
}

// ---------------------------------------------------------------------------
extern "C" void kernel_launch(void* const* d_in, const int* in_sizes, int n_in,
                              void* d_out, int out_size, void* d_ws, size_t ws_size,
                              hipStream_t stream)
{
    (void)in_sizes; (void)n_in; (void)out_size; (void)d_ws; (void)ws_size;

    const float* x  = (const float*)d_in[0];   // [16384, 2048] fp32
    const float* Wg = (const float*)d_in[1];   // [8192, 2048]  fp32
    const float* Wu = (const float*)d_in[2];   // [8192, 2048]  fp32
    const float* Wd = (const float*)d_in[3];   // [2048, 8192]  fp32
    const int* fg = (const int*)d_in[4];       // [8192]
    const int* sc = (const int*)d_in[5];       // [16384]
    float* out = (float*)d_out;                // [16384, 2048] fp32 (128 MiB)

    // h [8192*8192] bf16 = 128 MiB lives in d_out (dead until scatter).
    ushort_t* h = (ushort_t*)d_out;

    k_gather_cast<<<COMPACT, 256, 0, stream>>>(x, fg);
    k_cast<0><<<(INTER * HIDDEN / 8) / 256, 256, 0, stream>>>(Wg);
    k_cast<1><<<(INTER * HIDDEN / 8) / 256, 256, 0, stream>>>(Wu);
    k_cast<2><<<(HIDDEN * INTER / 8) / 256, 256, 0, stream>>>(Wd);

    k_gateup<<<dim3(INTER / 128, COMPACT / 128), 256, 0, stream>>>(h);
    k_down<<<dim3(HIDDEN / 128, COMPACT / 128), 256, 0, stream>>>(h);
    k_scatter<<<(NTOK * HIDDEN / 4) / 256, 256, 0, stream>>>(
        sc, (float4*)out);
}

// Round 2
// 1376.817 us; speedup vs baseline: 1.0884x; 1.0884x over previous
//
#include <hip/hip_runtime.h>
#include <hip/hip_bf16.h>
#include <stdint.h>

#define HIDDEN  2048
#define INTER   8192
#define COMPACT 8192
#define NTOK    16384

#define NT_GU (HIDDEN / 64)   // 32 K-tiles, gate/up GEMM
#define NT_DN (INTER / 64)    // 128 K-tiles, down GEMM

typedef unsigned short ushort_t;
typedef float  f32x4  __attribute__((ext_vector_type(4)));
typedef __bf16 bf16x8 __attribute__((ext_vector_type(8)));

#define VMCNT(n) asm volatile("s_waitcnt vmcnt(" #n ")" ::: "memory")
#define FENCE()  asm volatile("" ::: "memory")
#define BARRIER() do { FENCE(); __builtin_amdgcn_s_barrier(); FENCE(); } while (0)

// ---------------------------------------------------------------------------
// Scratch in static device globals (round-0 lesson: d_ws was too small and the
// overflow clobbered an input buffer after the first call).
// ---------------------------------------------------------------------------
__device__ __align__(16) ushort_t g_xc[(size_t)COMPACT * HIDDEN]; // 32 MiB bf16
__device__ __align__(16) ushort_t g_wg[(size_t)INTER * HIDDEN];   // 32 MiB bf16
__device__ __align__(16) ushort_t g_wu[(size_t)INTER * HIDDEN];   // 32 MiB bf16
__device__ __align__(16) ushort_t g_wd[(size_t)HIDDEN * INTER];   // 32 MiB bf16
__device__ __align__(16) float    g_dn[(size_t)COMPACT * HIDDEN]; // 64 MiB fp32

// fp32 -> bf16 round-to-nearest-even (finite inputs)
__device__ __forceinline__ ushort_t f2bf(float f) {
    uint32_t u = __builtin_bit_cast(uint32_t, f);
    uint32_t lsb = (u >> 16) & 1u;
    u += 0x7fffu + lsb;
    return (ushort_t)(u >> 16);
}

// Async global->LDS, 16B/lane. HW: wave-uniform LDS base + lane*16 (m104);
// per-lane GLOBAL address is free — that's where the swizzle lives (m173).
__device__ __forceinline__ void async_cp16(const void* g, void* l) {
    __builtin_amdgcn_global_load_lds(
        (__attribute__((address_space(1))) void*)((void*)g),
        (__attribute__((address_space(3))) void*)l,
        16, 0, 0);
}

// LDS tile layout: [rows][64] bf16 (128B rows). 16B chunk "slot" = byte/16 in
// row (0..7). Swizzle: data chunk c of row r lives at slot c ^ (r&7).
// Write side achieves this by pre-swizzling the global source chunk:
//   thread tid stages LDS slot (lane&7) of row (inst*64 + tid>>3) with global
//   chunk ((lane&7) ^ (lane>>3)).   [involution; lane-trace verified]
// Read side: frag (row, kchunk) -> slot = kchunk ^ (row&7) = kchunk ^ (lr&7).
// Result: 64 lanes spread 8-per-bank-quad = the b128 conflict floor.
__device__ __forceinline__ bf16x8 ldfrag(const ushort_t* m, int row, int slot) {
    return *(const bf16x8*)(m + row * 64 + slot * 8);
}

// ---------------------------------------------------------------------------
// Prepass 1: gather + fp32->bf16.  g_xc[c,:] = bf16(x[fg[c],:])
// ---------------------------------------------------------------------------
__global__ __launch_bounds__(256)
void k_gather_cast(const float* __restrict__ x, const int* __restrict__ fg)
{
    const int c = blockIdx.x;
    const int t = threadIdx.x;
    const float4* src = (const float4*)(x + (size_t)fg[c] * HIDDEN) + (t << 1);
    float4 a = src[0], b = src[1];
    union { ushort_t u[8]; uint4 v; } p;
    p.u[0] = f2bf(a.x); p.u[1] = f2bf(a.y); p.u[2] = f2bf(a.z); p.u[3] = f2bf(a.w);
    p.u[4] = f2bf(b.x); p.u[5] = f2bf(b.y); p.u[6] = f2bf(b.z); p.u[7] = f2bf(b.w);
    *((uint4*)(g_xc + (size_t)c * HIDDEN) + t) = p.v;
}

// ---------------------------------------------------------------------------
// Prepass 2: fp32->bf16 cast. W selects dest global (0=Wg, 1=Wu, 2=Wd).
// ---------------------------------------------------------------------------
template<int W>
__global__ __launch_bounds__(256)
void k_cast(const float* __restrict__ src)
{
    ushort_t* __restrict__ dst = (W == 0) ? g_wg : (W == 1) ? g_wu : g_wd;
    const size_t g = (size_t)blockIdx.x * 256 + threadIdx.x;
    const float4* s = (const float4*)src + (g << 1);
    float4 a = s[0], b = s[1];
    union { ushort_t u[8]; uint4 v; } p;
    p.u[0] = f2bf(a.x); p.u[1] = f2bf(a.y); p.u[2] = f2bf(a.z); p.u[3] = f2bf(a.w);
    p.u[4] = f2bf(b.x); p.u[5] = f2bf(b.y); p.u[6] = f2bf(b.z); p.u[7] = f2bf(b.w);
    *((uint4*)dst + g) = p.v;
}

// MFMA quadrant: 4 m-frags x 2 n-frags x 2 k-steps = 16 MFMA.
#define MFMA16(ACC, AF, BF)                                                    \
    _Pragma("unroll")                                                          \
    for (int i = 0; i < 4; ++i)                                                \
        _Pragma("unroll")                                                      \
        for (int j = 0; j < 2; ++j) {                                          \
            ACC[i][j] = __builtin_amdgcn_mfma_f32_16x16x32_bf16(AF[i][0], BF[j][0], ACC[i][j], 0, 0, 0); \
            ACC[i][j] = __builtin_amdgcn_mfma_f32_16x16x32_bf16(AF[i][1], BF[j][1], ACC[i][j], 0, 0, 0); \
        }

// ---------------------------------------------------------------------------
// Kernel 1: gate/up GEMM + silu-mul.  h[c,i] = silu(xc.Wg) * (xc.Wu)
// NT GEMM M=8192 N=8192 K=2048. BM=256 BN=128 BK=64, 512 thr / 8 waves,
// 128 KiB dbuf LDS, 1 block/CU. 4 phases per K-tile:
//   ph1 (m0,gate): read A(m0)+Bg ; stage A0+   ; vmcnt(4) ; bar ; 16 MFMA ; bar
//   ph2 (m0,up)  : read Bu       ; stage Bg+   ; vmcnt(4) ; bar ; 16 MFMA ; bar
//   ph3 (m1,gate): read A(m1)    ; stage Bu+   ;          ; bar ; 16 MFMA ; bar
//   ph4 (m1,up)  : (all cached)  ; stage A1+   ; vmcnt(4) ; bar ; 16 MFMA ; bar
// Steady-state invariant entering ph1(t): outstanding = [Bu(t), A1(t)] (4).
// Each vmcnt(4) drains exactly the half needed by the NEXT phase, leaving
// later-needed halves in flight (issue->consume distance 3-4 phases).
// Tail tile: vmcnt(2) at ph1, vmcnt(0) at ph2.
// ---------------------------------------------------------------------------
__global__ __launch_bounds__(512, 2)
void k_gateup(ushort_t* __restrict__ h)
{
    __shared__ __align__(16) ushort_t As[2][256 * 64];
    __shared__ __align__(16) ushort_t Gs[2][128 * 64];
    __shared__ __align__(16) ushort_t Us[2][128 * 64];

    const int tid  = threadIdx.x;
    const int lane = tid & 63;
    const int wv   = tid >> 6;
    const int wr   = wv >> 2;            // 0..1 (m within quadrant)
    const int wc   = wv & 3;             // 0..3 (n within quadrant)
    const int lr   = lane & 15;
    const int q    = lane >> 4;          // 0..3
    const int sl0  = q ^ (lr & 7);       // slot for kk=0
    const int sl1  = sl0 ^ 4;            // slot for kk=1
    const int srow = tid >> 3;           // staging row within 64-row chunk
    const int scol = ((lane & 7) ^ (lane >> 3)) << 3;  // pre-swizzled k-chunk
    const int lofs = tid * 8;            // staging LDS offset (ushorts)

    const int bm0 = blockIdx.y << 8;     // 256-row tile
    const int bn0 = blockIdx.x << 7;     // 128-col tile

    const ushort_t* pA = g_xc + (size_t)(bm0 + srow) * HIDDEN + scol;
    const ushort_t* pG = g_wg + (size_t)(bn0 + srow) * HIDDEN + scol;
    const ushort_t* pU = g_wu + (size_t)(bn0 + srow) * HIDDEN + scol;
    const size_t rS = (size_t)64 * HIDDEN;

    f32x4 ag0[4][2], ag1[4][2], au0[4][2], au1[4][2];
    #pragma unroll
    for (int i = 0; i < 4; ++i)
        #pragma unroll
        for (int j = 0; j < 2; ++j) {
            ag0[i][j] = (f32x4){0.f,0.f,0.f,0.f};
            ag1[i][j] = (f32x4){0.f,0.f,0.f,0.f};
            au0[i][j] = (f32x4){0.f,0.f,0.f,0.f};
            au1[i][j] = (f32x4){0.f,0.f,0.f,0.f};
        }

    // Prologue: tile 0 -> buf 0, full drain once.
    {
        ushort_t* An = As[0]; ushort_t* Gn = Gs[0]; ushort_t* Un = Us[0];
        async_cp16(pA,          An + lofs);
        async_cp16(pA + rS,     An + 4096 + lofs);
        async_cp16(pG,          Gn + lofs);
        async_cp16(pG + rS,     Gn + 4096 + lofs);
        async_cp16(pU,          Un + lofs);
        async_cp16(pU + rS,     Un + 4096 + lofs);
        async_cp16(pA + 2*rS,   An + 8192 + lofs);
        async_cp16(pA + 3*rS,   An + 12288 + lofs);
        pA += 64; pG += 64; pU += 64;
        VMCNT(0);
        BARRIER();
    }

    for (int t = 0; t < NT_GU; ++t) {
        const ushort_t* Ac = As[t & 1];
        const ushort_t* Gc = Gs[t & 1];
        const ushort_t* Uc = Us[t & 1];
        ushort_t* An = As[(t & 1) ^ 1];
        ushort_t* Gn = Gs[(t & 1) ^ 1];
        ushort_t* Un = Us[(t & 1) ^ 1];
        const bool more = (t + 1 < NT_GU);

        bf16x8 af[4][2], bg[2][2], bu[2][2];

        // ---- phase 1: (m0, gate) ----
        #pragma unroll
        for (int i = 0; i < 4; ++i) {
            const int row = wr * 64 + i * 16 + lr;
            af[i][0] = ldfrag(Ac, row, sl0);
            af[i][1] = ldfrag(Ac, row, sl1);
        }
        #pragma unroll
        for (int j = 0; j < 2; ++j) {
            const int row = wc * 32 + j * 16 + lr;
            bg[j][0] = ldfrag(Gc, row, sl0);
            bg[j][1] = ldfrag(Gc, row, sl1);
        }
        if (more) {
            async_cp16(pA,      An + lofs);
            async_cp16(pA + rS, An + 4096 + lofs);
            VMCNT(4);
        } else {
            VMCNT(2);
        }
        BARRIER();
        __builtin_amdgcn_s_setprio(1);
        MFMA16(ag0, af, bg);
        __builtin_amdgcn_s_setprio(0);
        BARRIER();

        // ---- phase 2: (m0, up) ----
        #pragma unroll
        for (int j = 0; j < 2; ++j) {
            const int row = wc * 32 + j * 16 + lr;
            bu[j][0] = ldfrag(Uc, row, sl0);
            bu[j][1] = ldfrag(Uc, row, sl1);
        }
        if (more) {
            async_cp16(pG,      Gn + lofs);
            async_cp16(pG + rS, Gn + 4096 + lofs);
            VMCNT(4);
        } else {
            VMCNT(0);
        }
        BARRIER();
        __builtin_amdgcn_s_setprio(1);
        MFMA16(au0, af, bu);
        __builtin_amdgcn_s_setprio(0);
        BARRIER();

        // ---- phase 3: (m1, gate) ----
        #pragma unroll
        for (int i = 0; i < 4; ++i) {
            const int row = 128 + wr * 64 + i * 16 + lr;
            af[i][0] = ldfrag(Ac, row, sl0);
            af[i][1] = ldfrag(Ac, row, sl1);
        }
        if (more) {
            async_cp16(pU,      Un + lofs);
            async_cp16(pU + rS, Un + 4096 + lofs);
        }
        BARRIER();
        __builtin_amdgcn_s_setprio(1);
        MFMA16(ag1, af, bg);
        __builtin_amdgcn_s_setprio(0);
        BARRIER();

        // ---- phase 4: (m1, up) ----
        if (more) {
            async_cp16(pA + 2*rS, An + 8192 + lofs);
            async_cp16(pA + 3*rS, An + 12288 + lofs);
        }
        VMCNT(4);
        BARRIER();
        __builtin_amdgcn_s_setprio(1);
        MFMA16(au1, af, bu);
        __builtin_amdgcn_s_setprio(0);
        BARRIER();

        pA += 64; pG += 64; pU += 64;
    }

    // Epilogue. C/D layout (m89): col = lane&15, row = (lane>>4)*4 + reg.
    const int or0 = bm0 + wr * 64 + (q << 2);
    const int oc  = bn0 + wc * 32 + lr;
    #define GU_STORE(AG, AU, MH)                                               \
        _Pragma("unroll")                                                      \
        for (int i = 0; i < 4; ++i)                                            \
            _Pragma("unroll")                                                  \
            for (int j = 0; j < 2; ++j)                                        \
                _Pragma("unroll")                                              \
                for (int r = 0; r < 4; ++r) {                                  \
                    float g = AG[i][j][r];                                     \
                    float u = AU[i][j][r];                                     \
                    float s = g / (1.0f + __expf(-g));                         \
                    h[(size_t)(or0 + (MH)*128 + i*16 + r) * INTER + (oc + j*16)] = f2bf(s * u); \
                }
    GU_STORE(ag0, au0, 0)
    GU_STORE(ag1, au1, 1)
    #undef GU_STORE
}

// ---------------------------------------------------------------------------
// Kernel 2: down GEMM.  g_dn[c,hc] = h[c,:] . Wd[hc,:]   (fp32 out)
// NT GEMM M=8192 N=2048 K=8192. BM=BN=256 BK=64. Same 4-phase skeleton:
//   ph1 (m0,n0): read A(m0)+B(n0); stage A0+ ; vmcnt(4) ; MFMA
//   ph2 (m0,n1): read B(n1)      ; stage B0+ ; vmcnt(4) ; MFMA
//   ph3 (m1,n0): read A(m1)      ; stage B1+ ;          ; MFMA
//   ph4 (m1,n1): (cached)        ; stage A1+ ; vmcnt(4) ; MFMA
// ---------------------------------------------------------------------------
__global__ __launch_bounds__(512, 2)
void k_down(const ushort_t* __restrict__ hbuf)
{
    __shared__ __align__(16) ushort_t As[2][256 * 64];
    __shared__ __align__(16) ushort_t Bs[2][256 * 64];

    const int tid  = threadIdx.x;
    const int lane = tid & 63;
    const int wv   = tid >> 6;
    const int wr   = wv >> 2;
    const int wc   = wv & 3;
    const int lr   = lane & 15;
    const int q    = lane >> 4;
    const int sl0  = q ^ (lr & 7);
    const int sl1  = sl0 ^ 4;
    const int srow = tid >> 3;
    const int scol = ((lane & 7) ^ (lane >> 3)) << 3;
    const int lofs = tid * 8;

    const int bm0 = blockIdx.y << 8;     // 0..31 * 256
    const int bn0 = blockIdx.x << 8;     // 0..7  * 256

    const ushort_t* pH = hbuf + (size_t)(bm0 + srow) * INTER + scol;
    const ushort_t* pW = g_wd + (size_t)(bn0 + srow) * INTER + scol;
    const size_t rS = (size_t)64 * INTER;

    f32x4 c00[4][2], c01[4][2], c10[4][2], c11[4][2];
    #pragma unroll
    for (int i = 0; i < 4; ++i)
        #pragma unroll
        for (int j = 0; j < 2; ++j) {
            c00[i][j] = (f32x4){0.f,0.f,0.f,0.f};
            c01[i][j] = (f32x4){0.f,0.f,0.f,0.f};
            c10[i][j] = (f32x4){0.f,0.f,0.f,0.f};
            c11[i][j] = (f32x4){0.f,0.f,0.f,0.f};
        }

    {
        ushort_t* An = As[0]; ushort_t* Bn = Bs[0];
        async_cp16(pH,          An + lofs);
        async_cp16(pH + rS,     An + 4096 + lofs);
        async_cp16(pW,          Bn + lofs);
        async_cp16(pW + rS,     Bn + 4096 + lofs);
        async_cp16(pW + 2*rS,   Bn + 8192 + lofs);
        async_cp16(pW + 3*rS,   Bn + 12288 + lofs);
        async_cp16(pH + 2*rS,   An + 8192 + lofs);
        async_cp16(pH + 3*rS,   An + 12288 + lofs);
        pH += 64; pW += 64;
        VMCNT(0);
        BARRIER();
    }

    for (int t = 0; t < NT_DN; ++t) {
        const ushort_t* Ac = As[t & 1];
        const ushort_t* Bc = Bs[t & 1];
        ushort_t* An = As[(t & 1) ^ 1];
        ushort_t* Bn = Bs[(t & 1) ^ 1];
        const bool more = (t + 1 < NT_DN);

        bf16x8 af[4][2], b0[2][2], b1[2][2];

        // ---- phase 1: (m0, n0) ----
        #pragma unroll
        for (int i = 0; i < 4; ++i) {
            const int row = wr * 64 + i * 16 + lr;
            af[i][0] = ldfrag(Ac, row, sl0);
            af[i][1] = ldfrag(Ac, row, sl1);
        }
        #pragma unroll
        for (int j = 0; j < 2; ++j) {
            const int row = wc * 32 + j * 16 + lr;
            b0[j][0] = ldfrag(Bc, row, sl0);
            b0[j][1] = ldfrag(Bc, row, sl1);
        }
        if (more) {
            async_cp16(pH,      An + lofs);
            async_cp16(pH + rS, An + 4096 + lofs);
            VMCNT(4);
        } else {
            VMCNT(2);
        }
        BARRIER();
        __builtin_amdgcn_s_setprio(1);
        MFMA16(c00, af, b0);
        __builtin_amdgcn_s_setprio(0);
        BARRIER();

        // ---- phase 2: (m0, n1) ----
        #pragma unroll
        for (int j = 0; j < 2; ++j) {
            const int row = 128 + wc * 32 + j * 16 + lr;
            b1[j][0] = ldfrag(Bc, row, sl0);
            b1[j][1] = ldfrag(Bc, row, sl1);
        }
        if (more) {
            async_cp16(pW,      Bn + lofs);
            async_cp16(pW + rS, Bn + 4096 + lofs);
            VMCNT(4);
        } else {
            VMCNT(0);
        }
        BARRIER();
        __builtin_amdgcn_s_setprio(1);
        MFMA16(c01, af, b1);
        __builtin_amdgcn_s_setprio(0);
        BARRIER();

        // ---- phase 3: (m1, n0) ----
        #pragma unroll
        for (int i = 0; i < 4; ++i) {
            const int row = 128 + wr * 64 + i * 16 + lr;
            af[i][0] = ldfrag(Ac, row, sl0);
            af[i][1] = ldfrag(Ac, row, sl1);
        }
        if (more) {
            async_cp16(pW + 2*rS, Bn + 8192 + lofs);
            async_cp16(pW + 3*rS, Bn + 12288 + lofs);
        }
        BARRIER();
        __builtin_amdgcn_s_setprio(1);
        MFMA16(c10, af, b0);
        __builtin_amdgcn_s_setprio(0);
        BARRIER();

        // ---- phase 4: (m1, n1) ----
        if (more) {
            async_cp16(pH + 2*rS, An + 8192 + lofs);
            async_cp16(pH + 3*rS, An + 12288 + lofs);
        }
        VMCNT(4);
        BARRIER();
        __builtin_amdgcn_s_setprio(1);
        MFMA16(c11, af, b1);
        __builtin_amdgcn_s_setprio(0);
        BARRIER();

        pH += 64; pW += 64;
    }

    const int or0 = bm0 + wr * 64 + (q << 2);
    const int oc  = bn0 + wc * 32 + lr;
    #define DN_STORE(CC, MH, NH)                                               \
        _Pragma("unroll")                                                      \
        for (int i = 0; i < 4; ++i)                                            \
            _Pragma("unroll")                                                  \
            for (int j = 0; j < 2; ++j)                                        \
                _Pragma("unroll")                                              \
                for (int r = 0; r < 4; ++r)                                    \
                    g_dn[(size_t)(or0 + (MH)*128 + i*16 + r) * HIDDEN + (oc + (NH)*128 + j*16)] = CC[i][j][r];
    DN_STORE(c00, 0, 0)
    DN_STORE(c01, 0, 1)
    DN_STORE(c10, 1, 0)
    DN_STORE(c11, 1, 1)
    #undef DN_STORE
}

// ---------------------------------------------------------------------------
// Kernel 3: scatter fp32 rows. out[n,:] = g_dn[sc[n],:]
// ---------------------------------------------------------------------------
__global__ __launch_bounds__(256)
void k_scatter(const int* __restrict__ sc,
               float4* __restrict__ out)
{
    const int gid = blockIdx.x * 256 + threadIdx.x;
    const int row = gid >> 9;
    const int ch  = gid & 511;
    const int s = sc[row];
    out[((size_t)row << 9) + ch] = ((const float4*)g_dn)[((size_t)s << 9) + ch];
}

// ---------------------------------------------------------------------------
extern "C" void kernel_launch(void* const* d_in, const int* in_sizes, int n_in,
                              void* d_out, int out_size, void* d_ws, size_t ws_size,
                              hipStream_t stream)
{
    (void)in_sizes; (void)n_in; (void)out_size; (void)d_ws; (void)ws_size;

    const float* x  = (const float*)d_in[0];   // [16384, 2048] fp32
    const float* Wg = (const float*)d_in[1];   // [8192, 2048]  fp32
    const float* Wu = (const float*)d_in[2];   // [8192, 2048]  fp32
    const float* Wd = (const float*)d_in[3];   // [2048, 8192]  fp32
    const int* fg = (const int*)d_in[4];       // [8192]
    const int* sc = (const int*)d_in[5];       // [16384]
    float* out = (float*)d_out;                // [16384, 2048] fp32

    // h [8192*8192] bf16 = 128 MiB lives in d_out (dead until scatter).
    ushort_t* h = (ushort_t*)d_out;

    k_gather_cast<<<COMPACT, 256, 0, stream>>>(x, fg);
    k_cast<0><<<(INTER * HIDDEN / 8) / 256, 256, 0, stream>>>(Wg);
    k_cast<1><<<(INTER * HIDDEN / 8) / 256, 256, 0, stream>>>(Wu);
    k_cast<2><<<(HIDDEN * INTER / 8) / 256, 256, 0, stream>>>(Wd);

    k_gateup<<<dim3(INTER / 128, COMPACT / 256), 512, 0, stream>>>(h);
    k_down<<<dim3(HIDDEN / 256, COMPACT / 256), 512, 0, stream>>>(h);
    k_scatter<<<(NTOK * HIDDEN / 4) / 256, 256, 0, stream>>>(
        sc, (float4*)out);
}